// Round 1
// baseline (406.520 us; speedup 1.0000x reference)
//
#include <hip/hip_runtime.h>
#include <stdint.h>

// Problem: B=32, T=128, C=64, DIN=DOUT=32, 4 gates.
#define T_STEPS 128
#define C_CH    64

using frag_ab = __attribute__((ext_vector_type(8))) short;  // 8 bf16
using frag_cd = __attribute__((ext_vector_type(4))) float;  // 4 fp32 acc
typedef __attribute__((ext_vector_type(4))) uint32_t u32x4;

// low short = u0[31:16], high short = u1[31:16]
__device__ __forceinline__ uint32_t pack_hi16(uint32_t u0, uint32_t u1) {
  return __builtin_amdgcn_perm(u1, u0, 0x07060302u);
}

__device__ __forceinline__ float fast_sigmoid(float v) {
  return __builtin_amdgcn_rcpf(1.0f + __expf(-v));
}
__device__ __forceinline__ float fast_tanh(float v) {
  return fmaf(2.0f, __builtin_amdgcn_rcpf(1.0f + __expf(-2.0f * v)), -1.0f);
}

// async global->LDS DMA, 16B per lane, dest = wave-uniform base + lane*16
__device__ __forceinline__ void async_load16(const float* g, void* l) {
  __builtin_amdgcn_global_load_lds((const __attribute__((address_space(1))) void*)g,
                                   (__attribute__((address_space(3))) void*)l, 16, 0, 0);
}

struct Frag2 { frag_ab hi, lo; };

// fp32x8 -> (hi bf16 x8, lo bf16 x8); hi = trunc16(f), lo = trunc16(f - hi)
__device__ __forceinline__ Frag2 split8(float4 a, float4 b) {
  uint32_t u0 = __float_as_uint(a.x), u1 = __float_as_uint(a.y);
  uint32_t u2 = __float_as_uint(a.z), u3 = __float_as_uint(a.w);
  uint32_t u4 = __float_as_uint(b.x), u5 = __float_as_uint(b.y);
  uint32_t u6 = __float_as_uint(b.z), u7 = __float_as_uint(b.w);
  uint32_t r0 = __float_as_uint(a.x - __uint_as_float(u0 & 0xFFFF0000u));
  uint32_t r1 = __float_as_uint(a.y - __uint_as_float(u1 & 0xFFFF0000u));
  uint32_t r2 = __float_as_uint(a.z - __uint_as_float(u2 & 0xFFFF0000u));
  uint32_t r3 = __float_as_uint(a.w - __uint_as_float(u3 & 0xFFFF0000u));
  uint32_t r4 = __float_as_uint(b.x - __uint_as_float(u4 & 0xFFFF0000u));
  uint32_t r5 = __float_as_uint(b.y - __uint_as_float(u5 & 0xFFFF0000u));
  uint32_t r6 = __float_as_uint(b.z - __uint_as_float(u6 & 0xFFFF0000u));
  uint32_t r7 = __float_as_uint(b.w - __uint_as_float(u7 & 0xFFFF0000u));
  union { u32x4 v; frag_ab f; } H, L;
  H.v[0] = pack_hi16(u0, u1); H.v[1] = pack_hi16(u2, u3);
  H.v[2] = pack_hi16(u4, u5); H.v[3] = pack_hi16(u6, u7);
  L.v[0] = pack_hi16(r0, r1); L.v[1] = pack_hi16(r2, r3);
  L.v[2] = pack_hi16(r4, r5); L.v[3] = pack_hi16(r6, r7);
  Frag2 o; o.hi = H.f; o.lo = L.f; return o;
}

// Grid: 256 blocks = q*64 + c  (keeps the 4 batch-quarters of a channel on one
// XCD so the 4x redundant weight reads hit that XCD's L2).
// Block: 512 threads = 8 waves. Wave w owns M-tile rows [16w,16w+16), with the
// frag-row->weight map  row x  <->  (g = x&3, i = 4w + (x>>2)).  This puts all
// 4 gates of output i in one lane's acc[0..3] -> no LDS gate exchange at all.
__global__ void __launch_bounds__(512)
lstm_kernel(const float* __restrict__ x, const float* __restrict__ xOps,
            const float* __restrict__ hOps, float* __restrict__ out) {
  // A: fp32 weights, [buf][plane 0=xOps,1=hOps][row=g*32+i][32 floats].
  // Within a row, 16B slots are XOR-swizzled by f(row)=g*2+(i&1) (bank fix);
  // the swizzle is applied by permuting the *global source* per lane, keeping
  // global_load_lds dests linear and loads fully coalesced (same 128B lines).
  __shared__ __align__(16) float Afp[2][2][128][32];   // 64 KiB
  // B: bf16 hi/lo planes, [buf][kt 0=x,1=h][hi/lo][kg][n][8 shorts] (16B rows)
  __shared__ __align__(16) short Bq[2][2][2][4][16][8]; // 16 KiB

  const int tid    = threadIdx.x;
  const int c      = blockIdx.x & 63;
  const int q      = blockIdx.x >> 6;
  const int w      = tid >> 6;        // wave = M-tile
  const int lane   = tid & 63;
  const int frag_n = lane & 15;       // batch col (valid < 8)
  const int quad   = lane >> 4;

  // ---- A staging: 4 x global_load_lds (1 KiB each) per wave per step ----
  int apl[4], arb[4];
  const float* aptr[4];
#pragma unroll
  for (int ii = 0; ii < 4; ++ii) {
    const int idx = w + 8 * ii;            // 0..31 instrs per block-step
    const int pl  = idx >> 4;              // 0=xOps, 1=hOps
    const int rb  = idx & 15;              // 8-row block
    apl[ii] = pl; arb[ii] = rb;
    const int r    = rb * 8 + (lane >> 3); // LDS row = g*32+i
    const int g    = r >> 5;
    const int i    = r & 31;
    const int f    = ((r >> 5) << 1) | (r & 1);   // slot swizzle f(row)
    const int slot = (lane & 7) ^ f;              // pre-swizzled source slot
    const float* base = pl ? hOps : xOps;
    aptr[ii] = base + ((size_t)g * T_STEPS * C_CH + c) * 1024
                    + (size_t)i * 32 + slot * 4;  // t=0
  }

  // ---- x staging (threads 0..127): thread -> (n, j-pair), VALU split path --
  const bool xthr = (tid < 128);
  const int  xn   = (tid >> 4) & 7;
  const int  xjp  = (tid & 15) * 2;
  const float* xptr = x + (size_t)(q * 8 + xn) * (T_STEPS * C_CH * 32)
                        + c * 32 + xjp;

  // ---- prologue: zero B (h0 = 0, pad rows n=8..15 stay 0), prefetch t=0 ----
  for (int idx = tid; idx < 4096; idx += 512) ((uint32_t*)Bq)[idx] = 0u;
  __syncthreads();

#pragma unroll
  for (int ii = 0; ii < 4; ++ii) {
    async_load16(aptr[ii], &Afp[0][apl[ii]][arb[ii] * 8][0]);
    aptr[ii] += (size_t)C_CH * 1024;
  }
  float2 xv = make_float2(0.f, 0.f);
  if (xthr) {
    float2 x0 = *(const float2*)xptr;
    uint32_t u0 = __float_as_uint(x0.x), u1 = __float_as_uint(x0.y);
    float r0 = x0.x - __uint_as_float(u0 & 0xFFFF0000u);
    float r1 = x0.y - __uint_as_float(u1 & 0xFFFF0000u);
    const int kg = xjp >> 3, sl = xjp & 7;
    *(uint32_t*)&Bq[0][0][0][kg][xn][sl] = pack_hi16(u0, u1);
    *(uint32_t*)&Bq[0][0][1][kg][xn][sl] =
        pack_hi16(__float_as_uint(r0), __float_as_uint(r1));
    xv = *(const float2*)(xptr + (size_t)C_CH * 32);   // x(1)
  }
  asm volatile("s_waitcnt vmcnt(0) lgkmcnt(0)\n\ts_barrier" ::: "memory");

  // ---- per-lane A-frag read constants ----
  // frag-row for this lane's A supply: (g=frag_n&3, i=4w+(frag_n>>2))
  const int frow = (frag_n & 3) * 32 + 4 * w + (frag_n >> 2);
  const int ff   = ((frow >> 5) << 1) | (frow & 1);
  const int so0  = (((quad << 1) ^ ff) << 2);        // float offsets in row
  const int so1  = ((((quad << 1) | 1) ^ ff) << 2);
  const int iq   = 4 * w + quad;                     // this lane's output dim
  const int hkg  = iq >> 3, hsl = iq & 7;            // h-writeback slot

  float c_state = 0.0f;

#pragma unroll 2
  for (int t = 0; t < T_STEPS; ++t) {
    const int cb = t & 1, nb = cb ^ 1;

    // -- issue staging for t+1 into buffer nb (in flight across this step) --
    if (t + 1 < T_STEPS) {
#pragma unroll
      for (int ii = 0; ii < 4; ++ii) {
        async_load16(aptr[ii], &Afp[nb][apl[ii]][arb[ii] * 8][0]);
        aptr[ii] += (size_t)C_CH * 1024;
      }
      if (xthr) {
        uint32_t u0 = __float_as_uint(xv.x), u1 = __float_as_uint(xv.y);
        float r0 = xv.x - __uint_as_float(u0 & 0xFFFF0000u);
        float r1 = xv.y - __uint_as_float(u1 & 0xFFFF0000u);
        const int kg = xjp >> 3, sl = xjp & 7;
        *(uint32_t*)&Bq[nb][0][0][kg][xn][sl] = pack_hi16(u0, u1);
        *(uint32_t*)&Bq[nb][0][1][kg][xn][sl] =
            pack_hi16(__float_as_uint(r0), __float_as_uint(r1));
        if (t + 2 < T_STEPS)
          xv = *(const float2*)(xptr + (size_t)(t + 2) * (C_CH * 32));
      }
    }

    // -- MFMA: 3-term hi/lo split, both kt planes into one acc --
    frag_cd acc = {0.f, 0.f, 0.f, 0.f};
#pragma unroll
    for (int kt = 0; kt < 2; ++kt) {
      const float* Ap = &Afp[cb][kt][frow][0];
      const float4 va = *(const float4*)(Ap + so0);
      const float4 vb = *(const float4*)(Ap + so1);
      Frag2 A = split8(va, vb);
      const frag_ab bh = *(const frag_ab*)&Bq[cb][kt][0][quad][frag_n][0];
      const frag_ab bl = *(const frag_ab*)&Bq[cb][kt][1][quad][frag_n][0];
      acc = __builtin_amdgcn_mfma_f32_16x16x32_bf16(A.hi, bh, acc, 0, 0, 0);
      acc = __builtin_amdgcn_mfma_f32_16x16x32_bf16(A.hi, bl, acc, 0, 0, 0);
      acc = __builtin_amdgcn_mfma_f32_16x16x32_bf16(A.lo, bh, acc, 0, 0, 0);
    }

    // -- cell update fully in-register: acc[r] = gate r for (i=iq, b=frag_n) --
    const float ig = fast_sigmoid(acc[0]);
    const float fg = fast_sigmoid(acc[1]);
    const float gg = fast_tanh(acc[2]);
    const float og = fast_sigmoid(acc[3]);
    c_state = fg * c_state + ig * gg;
    const float hval = og * fast_tanh(c_state);

    if (t == T_STEPS - 1) {
      if (frag_n < 8)
        out[((size_t)(q * 8 + frag_n) * C_CH + c) * 32 + iq] = hval;
    } else {
      // h writeback -> Bq[nb][1] as packed hi/lo bf16; pair (i, i+1) via ^16
      uint32_t uh = __float_as_uint(hval);
      float    rh = hval - __uint_as_float(uh & 0xFFFF0000u);
      uint32_t ur = __float_as_uint(rh);
      uint32_t pu = __shfl_xor(uh, 16);
      uint32_t pr = __shfl_xor(ur, 16);
      if (((quad & 1) == 0) && (frag_n < 8)) {
        *(uint32_t*)&Bq[nb][1][0][hkg][frag_n][hsl] = pack_hi16(uh, pu);
        *(uint32_t*)&Bq[nb][1][1][hkg][frag_n][hsl] = pack_hi16(ur, pr);
      }
      // Single barrier per step: all step-t writes target buffer nb, all
      // reads target cb; drain DMA loads + LDS writes, then cross.
      asm volatile("s_waitcnt vmcnt(0) lgkmcnt(0)\n\ts_barrier" ::: "memory");
    }
  }
}

extern "C" void kernel_launch(void* const* d_in, const int* in_sizes, int n_in,
                              void* d_out, int out_size, void* d_ws, size_t ws_size,
                              hipStream_t stream) {
  const float* x    = (const float*)d_in[0];
  const float* xOps = (const float*)d_in[1];
  const float* hOps = (const float*)d_in[2];
  lstm_kernel<<<dim3(256), dim3(512), 0, stream>>>(x, xOps, hOps, (float*)d_out);
}

// Round 2
// 335.380 us; speedup vs baseline: 1.2121x; 1.2121x over previous
//
#include <hip/hip_runtime.h>
#include <stdint.h>

// Problem: B=32, T=128, C=64, DIN=DOUT=32, 4 gates.
#define T_STEPS 128
#define C_CH    64
#define PIPE    4   // DMA ring depth for weights and x

using frag_ab = __attribute__((ext_vector_type(8))) short;  // 8 bf16
using frag_cd = __attribute__((ext_vector_type(4))) float;  // 4 fp32 acc
typedef __attribute__((ext_vector_type(4))) uint32_t u32x4;

// low short = u0[31:16], high short = u1[31:16]
__device__ __forceinline__ uint32_t pack_hi16(uint32_t u0, uint32_t u1) {
  return __builtin_amdgcn_perm(u1, u0, 0x07060302u);
}

__device__ __forceinline__ float fast_sigmoid(float v) {
  return __builtin_amdgcn_rcpf(1.0f + __expf(-v));
}
__device__ __forceinline__ float fast_tanh(float v) {
  return fmaf(2.0f, __builtin_amdgcn_rcpf(1.0f + __expf(-2.0f * v)), -1.0f);
}

// async global->LDS DMA, 16B per lane, dest = wave-uniform base + lane*16
__device__ __forceinline__ void async_load16(const float* g, void* l) {
  __builtin_amdgcn_global_load_lds((const __attribute__((address_space(1))) void*)g,
                                   (__attribute__((address_space(3))) void*)l, 16, 0, 0);
}

struct Frag2 { frag_ab hi, lo; };

// fp32x8 -> (hi bf16 x8, lo bf16 x8); hi = trunc16(f), lo = trunc16(f - hi)
__device__ __forceinline__ Frag2 split8(float4 a, float4 b) {
  uint32_t u0 = __float_as_uint(a.x), u1 = __float_as_uint(a.y);
  uint32_t u2 = __float_as_uint(a.z), u3 = __float_as_uint(a.w);
  uint32_t u4 = __float_as_uint(b.x), u5 = __float_as_uint(b.y);
  uint32_t u6 = __float_as_uint(b.z), u7 = __float_as_uint(b.w);
  uint32_t r0 = __float_as_uint(a.x - __uint_as_float(u0 & 0xFFFF0000u));
  uint32_t r1 = __float_as_uint(a.y - __uint_as_float(u1 & 0xFFFF0000u));
  uint32_t r2 = __float_as_uint(a.z - __uint_as_float(u2 & 0xFFFF0000u));
  uint32_t r3 = __float_as_uint(a.w - __uint_as_float(u3 & 0xFFFF0000u));
  uint32_t r4 = __float_as_uint(b.x - __uint_as_float(u4 & 0xFFFF0000u));
  uint32_t r5 = __float_as_uint(b.y - __uint_as_float(u5 & 0xFFFF0000u));
  uint32_t r6 = __float_as_uint(b.z - __uint_as_float(u6 & 0xFFFF0000u));
  uint32_t r7 = __float_as_uint(b.w - __uint_as_float(u7 & 0xFFFF0000u));
  union { u32x4 v; frag_ab f; } H, L;
  H.v[0] = pack_hi16(u0, u1); H.v[1] = pack_hi16(u2, u3);
  H.v[2] = pack_hi16(u4, u5); H.v[3] = pack_hi16(u6, u7);
  L.v[0] = pack_hi16(r0, r1); L.v[1] = pack_hi16(r2, r3);
  L.v[2] = pack_hi16(r4, r5); L.v[3] = pack_hi16(r6, r7);
  Frag2 o; o.hi = H.f; o.lo = L.f; return o;
}

// Grid: 256 blocks = q*64 + c (4 batch-quarters of a channel land on one XCD:
// blockIdx differing by 64 maps to the same XCD under round-robin, so the 4x
// redundant weight reads hit that XCD's L2).
// Block: 512 threads = 8 waves; wave w owns frag rows (g=frag_n&3, i=4w+frag_n>>2),
// so all 4 gates of output i land in one lane's acc[0..3] (no gate exchange).
//
// Pipeline: PIPE-deep global_load_lds ring with COUNTED vmcnt at the single
// per-step barrier (never vmcnt(0) in the loop) — 2 full steps of DMA stay in
// flight across every barrier. Tail iters issue dummy DMAs into a scratch sink
// so the per-wave vmcnt arithmetic stays uniform.
__global__ void __launch_bounds__(512)
lstm_kernel(const float* __restrict__ x, const float* __restrict__ xOps,
            const float* __restrict__ hOps, float* __restrict__ out) {
  // Weights fp32: [ring][plane 0=xOps,1=hOps][row=g*32+i][32 floats].
  // 16B slots within a row are XOR-swizzled by f(row)=((g<<1)|(i&1)) (bank fix);
  // applied by permuting the per-lane *global source*, keeping DMA dests linear.
  __shared__ __align__(16) float Afp[PIPE][2][128][32];   // 128 KiB
  // x fp32: [ring][n][32 floats], slots XOR-swizzled by (n&7); rows 8..15 = 0.
  __shared__ __align__(16) float Bx[PIPE][16][32];        // 8 KiB
  // h fp32: [parity][n][32 floats], same swizzle; rows 8..15 = 0.
  __shared__ __align__(16) float Bh[2][16][32];           // 4 KiB
  __shared__ __align__(16) float Scr[256];                // 1 KiB dummy DMA sink

  const int tid    = threadIdx.x;
  const int c      = blockIdx.x & 63;
  const int q      = blockIdx.x >> 6;
  const int w      = tid >> 6;
  const int lane   = tid & 63;
  const int frag_n = lane & 15;       // batch col (valid < 8)
  const int quad   = lane >> 4;

  // ---- weight staging: 4 x global_load_lds (1 KiB = 8 rows each) per wave --
  int apl[4], arb[4];
  const float* aptr[4];
#pragma unroll
  for (int ii = 0; ii < 4; ++ii) {
    const int idx = w + 8 * ii;            // 32 chunks cover both planes
    const int pl  = idx >> 4;
    const int rb  = idx & 15;
    apl[ii] = pl; arb[ii] = rb;
    const int r    = rb * 8 + (lane >> 3); // LDS row = g*32+i
    const int g    = r >> 5;
    const int i    = r & 31;
    const int f    = ((r >> 5) << 1) | (r & 1);
    const int slot = (lane & 7) ^ f;       // pre-swizzled source slot
    const float* base = pl ? hOps : xOps;
    aptr[ii] = base + ((size_t)g * T_STEPS * C_CH + c) * 1024
                    + (size_t)i * 32 + slot * 4;
  }

  // ---- x staging (wave 7): one 1 KiB DMA covers 8 batches x 32 floats ------
  const int xn  = lane >> 3, xsl = lane & 7;
  const float* xsrc = x + (((size_t)(q * 8 + xn) * T_STEPS) * C_CH + c) * 32
                        + ((xsl ^ (xn & 7)) << 2);
  const float* dummy_src = xOps;   // sink source for tail iters

  // ---- zero x/h planes (pad rows stay 0; h(0)=0), then prefetch PIPE-1 steps
  for (int i = tid; i < 2 * 16 * 32; i += 512) ((float*)Bh)[i] = 0.f;
  for (int i = tid; i < PIPE * 16 * 32; i += 512) ((float*)Bx)[i] = 0.f;
  __syncthreads();

#pragma unroll
  for (int s0 = 0; s0 < PIPE - 1; ++s0) {
#pragma unroll
    for (int ii = 0; ii < 4; ++ii) {
      async_load16(aptr[ii], &Afp[s0][apl[ii]][arb[ii] * 8][0]);
      aptr[ii] += (size_t)C_CH * 1024;
    }
    if (w == 7) { async_load16(xsrc, &Bx[s0][0][0]); xsrc += (size_t)C_CH * 32; }
  }

  // ---- per-lane read constants (A mapping identical to verified kernel) ----
  const int frow = (frag_n & 3) * 32 + 4 * w + (frag_n >> 2);
  const int ff   = ((frow >> 5) << 1) | (frow & 1);
  const int so0  = (((quad << 1) ^ ff) << 2);          // float offs in A row
  const int so1  = ((((quad << 1) | 1) ^ ff) << 2);
  const int bs0  = (((quad << 1) ^ (frag_n & 7)) << 2); // float offs in B row
  const int bs1  = ((((quad << 1) | 1) ^ (frag_n & 7)) << 2);
  const int iq   = 4 * w + quad;                        // this lane's output dim
  const int hwi  = ((w ^ (frag_n & 7)) << 2) | quad;    // h write float idx

  float c_state = 0.0f;

#pragma unroll 4
  for (int t = 0; t < T_STEPS; ++t) {
    const int cb = t & (PIPE - 1);
    const int hp = t & 1;

    // Counted wait: leave (PIPE-2) steps of DMA in flight across the barrier.
    // w<7: 4 loads/step -> vmcnt(8); w==7: 5 loads/step -> vmcnt(10).
    if (w == 7) asm volatile("s_waitcnt vmcnt(10) lgkmcnt(0)" ::: "memory");
    else        asm volatile("s_waitcnt vmcnt(8) lgkmcnt(0)" ::: "memory");
    asm volatile("s_barrier" ::: "memory");

    // Issue step t+PIPE-1 (after the barrier: its dest ring slot was last read
    // at step t-1, strictly before this barrier -> no WAR race).
    {
      const int s = t + PIPE - 1;
      if (s < T_STEPS) {
        const int sb = s & (PIPE - 1);
#pragma unroll
        for (int ii = 0; ii < 4; ++ii) {
          async_load16(aptr[ii], &Afp[sb][apl[ii]][arb[ii] * 8][0]);
          aptr[ii] += (size_t)C_CH * 1024;
        }
        if (w == 7) { async_load16(xsrc, &Bx[sb][0][0]); xsrc += (size_t)C_CH * 32; }
      } else {
        // keep vmcnt arithmetic exact in the tail: dummy DMAs into scratch
#pragma unroll
        for (int ii = 0; ii < 4; ++ii) async_load16(dummy_src, &Scr[0]);
        if (w == 7) async_load16(dummy_src, &Scr[0]);
      }
    }

    // ---- MFMA: X = [xop|hop] * [x;h], 3-term hi/lo split per plane ----
    frag_cd acc = {0.f, 0.f, 0.f, 0.f};
    {
      const float* Ap = &Afp[cb][0][frow][0];
      Frag2 A = split8(*(const float4*)(Ap + so0), *(const float4*)(Ap + so1));
      const float* Bp = &Bx[cb][frag_n][0];
      Frag2 Bf = split8(*(const float4*)(Bp + bs0), *(const float4*)(Bp + bs1));
      acc = __builtin_amdgcn_mfma_f32_16x16x32_bf16(A.hi, Bf.hi, acc, 0, 0, 0);
      acc = __builtin_amdgcn_mfma_f32_16x16x32_bf16(A.hi, Bf.lo, acc, 0, 0, 0);
      acc = __builtin_amdgcn_mfma_f32_16x16x32_bf16(A.lo, Bf.hi, acc, 0, 0, 0);
    }
    {
      const float* Ap = &Afp[cb][1][frow][0];
      Frag2 A = split8(*(const float4*)(Ap + so0), *(const float4*)(Ap + so1));
      const float* Bp = &Bh[hp][frag_n][0];
      Frag2 Bf = split8(*(const float4*)(Bp + bs0), *(const float4*)(Bp + bs1));
      acc = __builtin_amdgcn_mfma_f32_16x16x32_bf16(A.hi, Bf.hi, acc, 0, 0, 0);
      acc = __builtin_amdgcn_mfma_f32_16x16x32_bf16(A.hi, Bf.lo, acc, 0, 0, 0);
      acc = __builtin_amdgcn_mfma_f32_16x16x32_bf16(A.lo, Bf.hi, acc, 0, 0, 0);
    }

    // ---- cell update in-register: acc[r] = gate r for (i=iq, b=frag_n) ----
    const float ig = fast_sigmoid(acc[0]);
    const float fg = fast_sigmoid(acc[1]);
    const float gg = fast_tanh(acc[2]);
    const float og = fast_sigmoid(acc[3]);
    c_state = fg * c_state + ig * gg;
    const float hval = og * fast_tanh(c_state);

    if (t == T_STEPS - 1) {
      if (frag_n < 8)
        out[((size_t)(q * 8 + frag_n) * C_CH + c) * 32 + iq] = hval;
    } else {
      // h writeback (fp32, swizzled slot); visible at t+1 via lgkmcnt(0)+barrier
      if (frag_n < 8) Bh[hp ^ 1][frag_n][hwi] = hval;
    }
  }
}

extern "C" void kernel_launch(void* const* d_in, const int* in_sizes, int n_in,
                              void* d_out, int out_size, void* d_ws, size_t ws_size,
                              hipStream_t stream) {
  const float* x    = (const float*)d_in[0];
  const float* xOps = (const float*)d_in[1];
  const float* hOps = (const float*)d_in[2];
  lstm_kernel<<<dim3(256), dim3(512), 0, stream>>>(x, xOps, hOps, (float*)d_out);
}